// Round 7
// baseline (2088.615 us; speedup 1.0000x reference)
//
#include <hip/hip_runtime.h>

namespace {

constexpr int FHc = 3, FWc = 3;
constexpr int Bc = 8, Cc = 32, Hc = 32, Wc = 32, Oc = 64;
constexpr int HOc = 30, WOc = 30;
constexpr float SHIFTc = 0.1f;
constexpr int ROWW = 12;                 // padded LDS row (10 used) -> 48B, float4-aligned
constexpr int TILE_F = Cc * FHc * ROWW;  // 1152 floats per (lp|ln) tile

#define LOADROW(dst, base) do {                                         \
    const float4 _a = *reinterpret_cast<const float4*>(base);           \
    const float4 _b = *reinterpret_cast<const float4*>((base) + 4);     \
    const float2 _c = *reinterpret_cast<const float2*>((base) + 8);     \
    dst[0]=_a.x; dst[1]=_a.y; dst[2]=_a.z; dst[3]=_a.w;                 \
    dst[4]=_b.x; dst[5]=_b.y; dst[6]=_b.z; dst[7]=_b.w;                 \
    dst[8]=_c.x; dst[9]=_c.y; } while (0)

// R2-best structure (28.4 us) + runtime `reps` around the max-fold main loop.
// Max is idempotent: reps=2 recomputes identical folds -> output unchanged,
// main phase doubled -> kernel enters rocprof top-5 for real counters.
__global__ __launch_bounds__(512)
void bipolar_morph2d(const float* __restrict__ x,
                     const float* __restrict__ k1,
                     const float* __restrict__ k2,
                     const float* __restrict__ bias,
                     float* __restrict__ out,
                     int reps)
{
    __shared__ float sh[8192];
    float* lp = sh;
    float* ln = sh + TILE_F;

    const int tid = threadIdx.x;
    const int bid = blockIdx.x;
    const int wt  = bid & 3;             // which wo-tile of 8
    const int ho  = (bid >> 2) % HOc;
    const int b   = bid / (4 * HOc);
    const int wo0 = wt * 8;

    // ---- stage: lp = log(max(x,0.1)), ln = log(max(-x,0.1)) for 3x10 x C halo ----
    for (int e = tid; e < Cc * FHc * 10; e += 512) {
        const int c   = e / 30;
        const int rem = e - c * 30;
        const int i   = rem / 10;
        const int w   = rem - i * 10;
        int col = wo0 + w; if (col > Wc - 1) col = Wc - 1;
        const float xv = x[((b * Cc + c) * Hc + (ho + i)) * Wc + col];
        lp[(c * FHc + i) * ROWW + w] = __logf(fmaxf(xv,  SHIFTc));
        ln[(c * FHc + i) * ROWW + w] = __logf(fmaxf(-xv, SHIFTc));
    }
    __syncthreads();

    const int wv    = tid >> 6;   // wave id 0..7: owns c-chunk [4*wv, 4*wv+4)
    const int o     = tid & 63;   // lane = output channel
    const int cbase = wv * 4;

    float m11[8], m12[8], m21[8], m22[8];
    #pragma unroll
    for (int s = 0; s < 8; ++s) m11[s] = m12[s] = m21[s] = m22[s] = -1e30f;

    for (int rep = 0; rep < reps; ++rep) {
        #pragma unroll
        for (int cc = 0; cc < 4; cc += 2) {
            const int c0 = cbase + cc;
            #pragma unroll
            for (int i = 0; i < FHc; ++i) {
                float r_lp0[10], r_ln0[10], r_lp1[10], r_ln1[10];
                const float* bp0 = &lp[(c0 * FHc + i) * ROWW];
                const float* bn0 = &ln[(c0 * FHc + i) * ROWW];
                LOADROW(r_lp0, bp0);
                LOADROW(r_ln0, bn0);
                LOADROW(r_lp1, bp0 + FHc * ROWW);   // c0+1
                LOADROW(r_ln1, bn0 + FHc * ROWW);
                #pragma unroll
                for (int j = 0; j < FWc; ++j) {
                    const int p0 = ((i * FWc + j) * Cc + c0) * Oc + o;
                    const float k1a = k1[p0], k1b = k1[p0 + Oc];
                    const float k2a = k2[p0], k2b = k2[p0 + Oc];
                    #pragma unroll
                    for (int s = 0; s < 8; ++s) {
                        m11[s] = fmaxf(fmaxf(m11[s], r_lp0[j + s] + k1a), r_lp1[j + s] + k1b);
                        m12[s] = fmaxf(fmaxf(m12[s], r_lp0[j + s] + k2a), r_lp1[j + s] + k2b);
                        m21[s] = fmaxf(fmaxf(m21[s], r_ln0[j + s] + k1a), r_ln1[j + s] + k1b);
                        m22[s] = fmaxf(fmaxf(m22[s], r_ln0[j + s] + k2a), r_ln1[j + s] + k2b);
                    }
                }
            }
        }
    }

    // ---- cross-wave max reduction: 8 waves -> 4 -> 1, reusing one 32 KiB buffer ----
    __syncthreads();

    if (wv >= 4) {
        const int lw = wv - 4;
        #pragma unroll
        for (int s = 0; s < 8; ++s) {
            sh[((lw * 4 + 0) * 8 + s) * 64 + o] = m11[s];
            sh[((lw * 4 + 1) * 8 + s) * 64 + o] = m12[s];
            sh[((lw * 4 + 2) * 8 + s) * 64 + o] = m21[s];
            sh[((lw * 4 + 3) * 8 + s) * 64 + o] = m22[s];
        }
    }
    __syncthreads();
    if (wv < 4) {
        #pragma unroll
        for (int s = 0; s < 8; ++s) {
            m11[s] = fmaxf(m11[s], sh[((wv * 4 + 0) * 8 + s) * 64 + o]);
            m12[s] = fmaxf(m12[s], sh[((wv * 4 + 1) * 8 + s) * 64 + o]);
            m21[s] = fmaxf(m21[s], sh[((wv * 4 + 2) * 8 + s) * 64 + o]);
            m22[s] = fmaxf(m22[s], sh[((wv * 4 + 3) * 8 + s) * 64 + o]);
        }
    }
    __syncthreads();
    if (wv < 4) {
        #pragma unroll
        for (int s = 0; s < 8; ++s) {
            sh[((wv * 4 + 0) * 8 + s) * 64 + o] = m11[s];
            sh[((wv * 4 + 1) * 8 + s) * 64 + o] = m12[s];
            sh[((wv * 4 + 2) * 8 + s) * 64 + o] = m21[s];
            sh[((wv * 4 + 3) * 8 + s) * 64 + o] = m22[s];
        }
    }
    __syncthreads();

    // ---- finalize: each wave owns one spatial position s = wv ----
    const int s  = wv;
    const int wo = wo0 + s;
    if (wo < WOc) {
        const float bo = bias[o];
        float f[4];
        #pragma unroll
        for (int br = 0; br < 4; ++br) {
            const float v0 = sh[((0 * 4 + br) * 8 + s) * 64 + o];
            const float v1 = sh[((1 * 4 + br) * 8 + s) * 64 + o];
            const float v2 = sh[((2 * 4 + br) * 8 + s) * 64 + o];
            const float v3 = sh[((3 * 4 + br) * 8 + s) * 64 + o];
            f[br] = fmaxf(fmaxf(v0, v1), fmaxf(v2, v3));
        }
        out[((b * Oc + o) * HOc + ho) * WOc + wo] =
            __expf(f[0]) - __expf(f[1]) - __expf(f[2]) + __expf(f[3]) + bo;
    }
}

} // namespace

extern "C" void kernel_launch(void* const* d_in, const int* in_sizes, int n_in,
                              void* d_out, int out_size, void* d_ws, size_t ws_size,
                              hipStream_t stream) {
    const float* x    = (const float*)d_in[0];
    const float* k1   = (const float*)d_in[1];
    const float* k2   = (const float*)d_in[2];
    const float* bias = (const float*)d_in[3];
    float* out        = (float*)d_out;

    const int nblocks = Bc * HOc * 4;   // 960
    // reps=2: idempotent re-fold; doubles main phase so rocprof top-5 shows
    // this kernel's counters. Output identical to reps=1.
    bipolar_morph2d<<<dim3(nblocks), dim3(512), 0, stream>>>(x, k1, k2, bias, out, 2);
}

// Round 8
// 35.448 us; speedup vs baseline: 58.9212x; 58.9212x over previous
//
#include <hip/hip_runtime.h>

namespace {

constexpr int FHc = 3, FWc = 3;
constexpr int Bc = 8, Cc = 32, Hc = 32, Wc = 32, Oc = 64;
constexpr int HOc = 30, WOc = 30;
constexpr float SHIFTc = 0.1f;
constexpr int ROWW = 12;                 // padded LDS row (10 used) -> 48B
constexpr int TILE_F = Cc * FHc * ROWW;  // 1152 floats per tile
constexpr int NK = FHc * FWc * Cc * Oc;  // 18432

// ---- prep: kt[p] = (exp(k1[p]), exp(k2[p])) ----
// exp(max_p(log(max(±x,.1)) + k)) == max_p(max(±x,.1) * e^k)  (exp monotone)
__global__ __launch_bounds__(256)
void prep_expk(const float* __restrict__ k1, const float* __restrict__ k2,
               float2* __restrict__ kt)
{
    const int t = blockIdx.x * 256 + threadIdx.x;
    if (t < NK) kt[t] = make_float2(__expf(k1[t]), __expf(k2[t]));
}

#define LOADROW(dst, base) do {                                         \
    const float4 _a = *reinterpret_cast<const float4*>(base);           \
    const float4 _b = *reinterpret_cast<const float4*>((base) + 4);     \
    const float2 _c = *reinterpret_cast<const float2*>((base) + 8);     \
    dst[0]=_a.x; dst[1]=_a.y; dst[2]=_a.z; dst[3]=_a.w;                 \
    dst[4]=_b.x; dst[5]=_b.y; dst[6]=_b.z; dst[7]=_b.w;                 \
    dst[8]=_c.x; dst[9]=_c.y; } while (0)

// Branch-split: waves 0-3 fold (y11,y12) over mp; waves 4-7 fold (y21,y22)
// over mn. 16 accs + 10 row + 6 k ~= 45 live VGPR -> cap 64 (empirical
// formula cap = 256/arg2) gives 8 waves/EU -> 4 blocks/CU -> 960 blocks
// fully resident in one round.
__global__ __launch_bounds__(512, 4)
void bipolar_main(const float* __restrict__ x, const float2* __restrict__ kt,
                  const float* __restrict__ bias, float* __restrict__ out)
{
    // 32 KiB: mp/mn tiles (2*1152 floats) first, then 8192-float reduce buffer.
    __shared__ float sh[8192];
    float* mp = sh;
    float* mn = sh + TILE_F;

    const int tid = threadIdx.x;
    const int bid = blockIdx.x;
    const int wt  = bid & 3;             // wo-tile of 8
    const int ho  = (bid >> 2) % HOc;
    const int b   = bid / (4 * HOc);
    const int wo0 = wt * 8;

    // ---- stage: mp = max(x,0.1), mn = max(-x,0.1), 3x10 x C halo (no logs) ----
    for (int e = tid; e < Cc * FHc * 10; e += 512) {
        const int c   = e / 30;
        const int rem = e - c * 30;
        const int i   = rem / 10;
        const int w   = rem - i * 10;
        int col = wo0 + w; if (col > Wc - 1) col = Wc - 1;  // clamp feeds only unused s
        const float xv = x[((b * Cc + c) * Hc + (ho + i)) * Wc + col];
        mp[(c * FHc + i) * ROWW + w] = fmaxf(xv,  SHIFTc);
        mn[(c * FHc + i) * ROWW + w] = fmaxf(-xv, SHIFTc);
    }
    __syncthreads();

    const int wv   = tid >> 6;    // 0..7
    const int o    = tid & 63;    // lane = output channel
    const int half = wv >> 2;     // 0: (y11,y12) from mp ; 1: (y21,y22) from mn
    const int cw   = wv & 3;      // c-chunk of 8
    const int cbase = cw * 8;
    const float* tile = half ? mn : mp;

    float ma[8], mb[8];           // acc for tables e1 / e2 (linear domain, >0)
    #pragma unroll
    for (int s = 0; s < 8; ++s) ma[s] = mb[s] = 0.0f;

    #pragma unroll 2
    for (int cc = 0; cc < 8; ++cc) {
        const int c = cbase + cc;
        #pragma unroll
        for (int i = 0; i < FHc; ++i) {
            float r[10];
            LOADROW(r, &tile[(c * FHc + i) * ROWW]);
            const int kb = (i * FWc * Cc + c) * Oc + o;   // float2 index, j=0
            const float2 e0 = kt[kb];
            const float2 e1 = kt[kb + Cc * Oc];
            const float2 e2 = kt[kb + 2 * Cc * Oc];
            #pragma unroll
            for (int s = 0; s < 8; ++s) {
                // max3(m, a, max(b,c)): 3 mul + 2 max-ops per 3 taps
                ma[s] = fmaxf(fmaxf(ma[s], r[s] * e0.x), fmaxf(r[s+1] * e1.x, r[s+2] * e2.x));
                mb[s] = fmaxf(fmaxf(mb[s], r[s] * e0.y), fmaxf(r[s+1] * e1.y, r[s+2] * e2.y));
            }
        }
    }

    // ---- publish partials: [cw][half][table][s][o] (reuses tile region) ----
    __syncthreads();   // all tile reads done
    #pragma unroll
    for (int s = 0; s < 8; ++s) {
        sh[((cw * 4 + half * 2 + 0) * 8 + s) * 64 + o] = ma[s];
        sh[((cw * 4 + half * 2 + 1) * 8 + s) * 64 + o] = mb[s];
    }
    __syncthreads();

    // ---- finalize: wave wv owns spatial position s = wv ----
    const int s  = wv;
    const int wo = wo0 + s;
    if (wo < WOc) {
        float y11 = 0.f, y12 = 0.f, y21 = 0.f, y22 = 0.f;
        #pragma unroll
        for (int q = 0; q < 4; ++q) {
            y11 = fmaxf(y11, sh[((q * 4 + 0) * 8 + s) * 64 + o]);
            y12 = fmaxf(y12, sh[((q * 4 + 1) * 8 + s) * 64 + o]);
            y21 = fmaxf(y21, sh[((q * 4 + 2) * 8 + s) * 64 + o]);
            y22 = fmaxf(y22, sh[((q * 4 + 3) * 8 + s) * 64 + o]);
        }
        // linear domain already == exp(log-domain max); no exp needed
        out[((b * Oc + o) * HOc + ho) * WOc + wo] = y11 - y12 - y21 + y22 + bias[o];
    }
}

} // namespace

extern "C" void kernel_launch(void* const* d_in, const int* in_sizes, int n_in,
                              void* d_out, int out_size, void* d_ws, size_t ws_size,
                              hipStream_t stream) {
    const float* x    = (const float*)d_in[0];
    const float* k1   = (const float*)d_in[1];
    const float* k2   = (const float*)d_in[2];
    const float* bias = (const float*)d_in[3];
    float2* kt        = (float2*)d_ws;
    float* out        = (float*)d_out;

    prep_expk<<<dim3((NK + 255) / 256), dim3(256), 0, stream>>>(k1, k2, kt);

    const int nblocks = Bc * HOc * 4;   // 960
    bipolar_main<<<dim3(nblocks), dim3(512), 0, stream>>>(x, kt, bias, out);
}

// Round 9
// 29.667 us; speedup vs baseline: 70.4025x; 1.1949x over previous
//
#include <hip/hip_runtime.h>

namespace {

constexpr int FHc = 3, FWc = 3;
constexpr int Bc = 8, Cc = 32, Hc = 32, Wc = 32, Oc = 64;
constexpr int HOc = 30, WOc = 30;
constexpr float SHIFTc = 0.1f;
constexpr int ROWW = 12;                 // padded LDS row (10 used) -> 48B
constexpr int TILE_F = Cc * FHc * ROWW;  // 1152 floats per (lp|ln) tile

#define LOADROW(dst, base) do {                                         \
    const float4 _a = *reinterpret_cast<const float4*>(base);           \
    const float4 _b = *reinterpret_cast<const float4*>((base) + 4);     \
    const float2 _c = *reinterpret_cast<const float2*>((base) + 8);     \
    dst[0]=_a.x; dst[1]=_a.y; dst[2]=_a.z; dst[3]=_a.w;                 \
    dst[4]=_b.x; dst[5]=_b.y; dst[6]=_b.z; dst[7]=_b.w;                 \
    dst[8]=_c.x; dst[9]=_c.y; } while (0)

// R2 geometry (512thr/960blk/SW=8/log-domain 6add+3max3 scheme) + branch-split
// waves: half=wv>>2 picks polarity tile; wave folds only (k1,k2) for that
// polarity over 8 channels -> 16 accs (was 32), half the LDS row reads.
// Live ~58 VGPR; (512,4) caps at 64 (empirical cap=256/arg2) -> 8 waves/EU
// -> 4 blocks/CU -> all 960 blocks in one dispatch round.
__global__ __launch_bounds__(512, 4)
void bipolar_morph2d(const float* __restrict__ x,
                     const float* __restrict__ k1,
                     const float* __restrict__ k2,
                     const float* __restrict__ bias,
                     float* __restrict__ out)
{
    __shared__ float sh[8192];           // 32 KiB: tiles, then reduce buffer
    float* lp = sh;
    float* ln = sh + TILE_F;

    const int tid = threadIdx.x;
    const int bid = blockIdx.x;
    const int wt  = bid & 3;             // wo-tile of 8
    const int ho  = (bid >> 2) % HOc;
    const int b   = bid / (4 * HOc);
    const int wo0 = wt * 8;

    // ---- stage: lp = log(max(x,.1)), ln = log(max(-x,.1)), 3x10 x C halo ----
    for (int e = tid; e < Cc * FHc * 10; e += 512) {
        const int c   = e / 30;
        const int rem = e - c * 30;
        const int i   = rem / 10;
        const int w   = rem - i * 10;
        int col = wo0 + w; if (col > Wc - 1) col = Wc - 1;  // clamp feeds only unused s
        const float xv = x[((b * Cc + c) * Hc + (ho + i)) * Wc + col];
        lp[(c * FHc + i) * ROWW + w] = __logf(fmaxf(xv,  SHIFTc));
        ln[(c * FHc + i) * ROWW + w] = __logf(fmaxf(-xv, SHIFTc));
    }
    __syncthreads();

    const int wv    = tid >> 6;          // 0..7
    const int o     = tid & 63;          // lane = output channel
    const int half  = wv >> 2;           // 0: lp (y11,y12)  1: ln (y21,y22)
    const int cw    = wv & 3;            // c-chunk of 8
    const int cbase = cw * 8;
    const float* tile = half ? ln : lp;
    const float* kt1  = k1 + o;          // lane-offset bases; idx = i*6144+j*2048+c*64
    const float* kt2  = k2 + o;

    float m1[8], m2[8];
    #pragma unroll
    for (int s = 0; s < 8; ++s) m1[s] = m2[s] = -1e30f;

    #pragma unroll
    for (int p = 0; p < 4; ++p) {        // channel pairs
        const int c0 = cbase + 2 * p;
        #pragma unroll
        for (int i = 0; i < FHc; ++i) {
            float r0[10], r1[10];
            LOADROW(r0, &tile[(c0 * FHc + i) * ROWW]);
            LOADROW(r1, &tile[((c0 + 1) * FHc + i) * ROWW]);

            const int kb = i * 6144 + c0 * 64;          // j-stride 2048, c-stride 64
            const float a10 = kt1[kb],        a11 = kt1[kb + 2048],      a12 = kt1[kb + 4096];
            const float b10 = kt1[kb + 64],   b11 = kt1[kb + 2112],      b12 = kt1[kb + 4160];
            const float a20 = kt2[kb],        a21 = kt2[kb + 2048],      a22 = kt2[kb + 4096];
            const float b20 = kt2[kb + 64],   b21 = kt2[kb + 2112],      b22 = kt2[kb + 4160];

            #pragma unroll
            for (int s = 0; s < 8; ++s) {
                // 6 adds + 3 v_max3 per (s, table)
                m1[s] = fmaxf(fmaxf(m1[s], r0[s] + a10),     r0[s + 1] + a11);
                m1[s] = fmaxf(fmaxf(m1[s], r0[s + 2] + a12), r1[s]     + b10);
                m1[s] = fmaxf(fmaxf(m1[s], r1[s + 1] + b11), r1[s + 2] + b12);
                m2[s] = fmaxf(fmaxf(m2[s], r0[s] + a20),     r0[s + 1] + a21);
                m2[s] = fmaxf(fmaxf(m2[s], r0[s + 2] + a22), r1[s]     + b20);
                m2[s] = fmaxf(fmaxf(m2[s], r1[s + 1] + b21), r1[s + 2] + b22);
            }
        }
    }

    // ---- publish partials: [half*2+table][cw][s][o] = 16*8*64 = 8192 floats ----
    __syncthreads();                     // tile reads done; overwrite sh
    #pragma unroll
    for (int s = 0; s < 8; ++s) {
        sh[(((half * 2 + 0) * 4 + cw) * 8 + s) * 64 + o] = m1[s];
        sh[(((half * 2 + 1) * 4 + cw) * 8 + s) * 64 + o] = m2[s];
    }
    __syncthreads();

    // ---- finalize: wave wv owns spatial position s = wv ----
    const int s  = wv;
    const int wo = wo0 + s;
    if (wo < WOc) {
        float f[4];
        #pragma unroll
        for (int g = 0; g < 4; ++g) {    // g: 0=y11 1=y12 2=y21 3=y22
            const float v0 = sh[((g * 4 + 0) * 8 + s) * 64 + o];
            const float v1 = sh[((g * 4 + 1) * 8 + s) * 64 + o];
            const float v2 = sh[((g * 4 + 2) * 8 + s) * 64 + o];
            const float v3 = sh[((g * 4 + 3) * 8 + s) * 64 + o];
            f[g] = fmaxf(fmaxf(v0, v1), fmaxf(v2, v3));
        }
        out[((b * Oc + o) * HOc + ho) * WOc + wo] =
            __expf(f[0]) - __expf(f[1]) - __expf(f[2]) + __expf(f[3]) + bias[o];
    }
}

} // namespace

extern "C" void kernel_launch(void* const* d_in, const int* in_sizes, int n_in,
                              void* d_out, int out_size, void* d_ws, size_t ws_size,
                              hipStream_t stream) {
    const float* x    = (const float*)d_in[0];
    const float* k1   = (const float*)d_in[1];
    const float* k2   = (const float*)d_in[2];
    const float* bias = (const float*)d_in[3];
    float* out        = (float*)d_out;

    const int nblocks = Bc * HOc * 4;   // 960
    bipolar_morph2d<<<dim3(nblocks), dim3(512), 0, stream>>>(x, k1, k2, bias, out);
}